// Round 1
// baseline (2037.964 us; speedup 1.0000x reference)
//
#include <hip/hip_runtime.h>
#include <cstdint>
#include <cstddef>

#define HIDDEN 2048
#define INTER 8192
#define NTOK 8192
#define RET 128
#define NKEYS 64
#define TOPK 8

typedef __bf16 bf16_t;
typedef bf16_t bf16x8 __attribute__((ext_vector_type(8)));
typedef float floatx4 __attribute__((ext_vector_type(4)));

__device__ inline unsigned short f2bf(float f) {
  union { float f; unsigned u; } v; v.f = f;
  unsigned r = v.u + 0x7FFFu + ((v.u >> 16) & 1u);  // RNE
  return (unsigned short)(r >> 16);
}
__device__ inline float bf2f(unsigned short s) {
  union { unsigned u; float f; } v; v.u = ((unsigned)s) << 16;
  return v.f;
}

// async global->LDS, 16B per lane. lds must be the wave-uniform base; HW puts
// lane i's 16B at base + i*16.
__device__ inline void gld_lds16(unsigned short* lds, const unsigned short* g) {
  auto* l3 = reinterpret_cast<__attribute__((address_space(3))) unsigned int*>(
      reinterpret_cast<uintptr_t>(lds));
  auto* g1 = reinterpret_cast<const __attribute__((address_space(1))) unsigned int*>(
      reinterpret_cast<uintptr_t>(g));
  __builtin_amdgcn_global_load_lds(g1, l3, 16, 0, 0);
}

// ---------------- fp32 -> bf16 convert (contiguous) ----------------
__global__ __launch_bounds__(256) void cvt_bf16(const float* __restrict__ in,
                                                unsigned short* __restrict__ out,
                                                int count4) {
  for (int i = blockIdx.x * blockDim.x + threadIdx.x; i < count4;
       i += gridDim.x * blockDim.x) {
    float4 v = reinterpret_cast<const float4*>(in)[i];
    ushort4 o;
    o.x = f2bf(v.x); o.y = f2bf(v.y); o.z = f2bf(v.z); o.w = f2bf(v.w);
    reinterpret_cast<ushort4*>(out)[i] = o;
  }
}

// ---------------- fp32 [R][C] -> bf16 [C][R] transpose-convert ----------------
__global__ __launch_bounds__(256) void transpose_cvt(const float* __restrict__ in,
                                                     unsigned short* __restrict__ out,
                                                     int R, int C) {
  __shared__ float tile[32][33];
  int c0 = blockIdx.x * 32, r0 = blockIdx.y * 32;
  int tx = threadIdx.x, ty = threadIdx.y;  // block (32,8)
#pragma unroll
  for (int it = 0; it < 4; ++it)
    tile[ty + it * 8][tx] = in[(size_t)(r0 + ty + it * 8) * C + c0 + tx];
  __syncthreads();
#pragma unroll
  for (int it = 0; it < 4; ++it)
    out[(size_t)(c0 + ty + it * 8) * R + r0 + tx] = f2bf(tile[tx][ty + it * 8]);
}

// ---------------- bf16 GEMM: C[M,N] = A[M,K] * B[N,K]^T ----------------
// 128x128 tile, BK=64, 4 waves each computing 64x64 via 4x4 mfma_16x16x32_bf16.
enum { EPI_F32 = 0, EPI_BF16 = 1, EPI_SILU = 2, EPI_ADDF32 = 3 };

template <int MODE>
__global__ __launch_bounds__(256) void gemm_bt(const unsigned short* __restrict__ A,
                                               const unsigned short* __restrict__ B,
                                               float* __restrict__ Cf,
                                               unsigned short* __restrict__ Cb,
                                               int M, int N, int K) {
  __shared__ unsigned short As[128 * 64];
  __shared__ unsigned short Bs[128 * 64];
  const int tid = threadIdx.x;
  const int lane = tid & 63, wid = tid >> 6;
  const int wm = wid >> 1, wn = wid & 1;
  const int m0 = blockIdx.y * 128, n0 = blockIdx.x * 128;
  const int lr = lane & 15, q = lane >> 4;

  floatx4 acc[4][4];
#pragma unroll
  for (int i = 0; i < 4; ++i)
#pragma unroll
    for (int j = 0; j < 4; ++j) acc[i][j] = (floatx4){0.f, 0.f, 0.f, 0.f};

  for (int k0 = 0; k0 < K; k0 += 64) {
    // stage A,B tiles (128x64 bf16 each = 1024 x 16B chunks each)
#pragma unroll
    for (int s = 0; s < 4; ++s) {
      int c = s * 256 + wid * 64 + lane;
      int row = c >> 3, cc = c & 7;
      gld_lds16(&As[(s * 256 + wid * 64) * 8],
                A + (size_t)(m0 + row) * K + k0 + cc * 8);
      gld_lds16(&Bs[(s * 256 + wid * 64) * 8],
                B + (size_t)(n0 + row) * K + k0 + cc * 8);
    }
    __syncthreads();  // drains vmcnt -> LDS tiles complete
#pragma unroll
    for (int kc = 0; kc < 2; ++kc) {
      bf16x8 af[4], bfv[4];
#pragma unroll
      for (int t = 0; t < 4; ++t) {
        af[t] = *reinterpret_cast<const bf16x8*>(
            &As[(wm * 64 + t * 16 + lr) * 64 + kc * 32 + q * 8]);
        bfv[t] = *reinterpret_cast<const bf16x8*>(
            &Bs[(wn * 64 + t * 16 + lr) * 64 + kc * 32 + q * 8]);
      }
#pragma unroll
      for (int i = 0; i < 4; ++i)
#pragma unroll
        for (int j = 0; j < 4; ++j)
          acc[i][j] = __builtin_amdgcn_mfma_f32_16x16x32_bf16(af[i], bfv[j],
                                                              acc[i][j], 0, 0, 0);
    }
    __syncthreads();  // compute done before next-iter staging overwrites LDS
  }

  // epilogue: C/D layout col=lane&15, row=(lane>>4)*4+reg
#pragma unroll
  for (int i = 0; i < 4; ++i) {
    int rbase = m0 + wm * 64 + i * 16 + q * 4;
#pragma unroll
    for (int j = 0; j < 4; ++j) {
      int col = n0 + wn * 64 + j * 16 + lr;
#pragma unroll
      for (int r = 0; r < 4; ++r) {
        size_t idx = (size_t)(rbase + r) * N + col;
        float v = acc[i][j][r];
        if (MODE == EPI_F32) {
          Cf[idx] = v;
        } else if (MODE == EPI_BF16) {
          Cb[idx] = f2bf(v);
        } else if (MODE == EPI_SILU) {
          float g = bf2f(Cb[idx]);          // gate value written by prior GEMM
          float sg = g / (1.f + __expf(-g));
          Cb[idx] = f2bf(sg * v);           // h = silu(g) * u, in place
        } else {  // EPI_ADDF32
          Cf[idx] = v + Cf[idx];            // += expert states already in d_out
        }
      }
    }
  }
}

// ---------------- routing: per-token 2x(64x64 matvec) + top8 + pair top8 ----------------
__global__ __launch_bounds__(256) void routing_kernel(const float* __restrict__ Q,
                                                      const float* __restrict__ keys,
                                                      int* __restrict__ topi,
                                                      float* __restrict__ topw) {
  __shared__ float k0s[64 * 64];
  __shared__ float k1s[64 * 64];
  for (int i = threadIdx.x; i < 64 * 64; i += 256) {
    k0s[i] = keys[i];
    k1s[i] = keys[64 * 64 + i];
  }
  __syncthreads();
  const int lane = threadIdx.x & 63, wid = threadIdx.x >> 6;
  const int gw = blockIdx.x * 4 + wid;  // 1024 waves total
  const float NEG = -__builtin_inff();

  for (int n = gw; n < NTOK; n += 1024) {
    // bug-faithful reshape: queries[0,n,d]=Q[n/2, (n&1)*64+d]; queries[1,n,d]=Q[N/2+n/2, ...]
    int cbase = (n & 1) * 64;
    float qx = Q[(size_t)(n >> 1) * RET + cbase + lane];
    float qy = Q[(size_t)(NTOK / 2 + (n >> 1)) * RET + cbase + lane];
    float rx = 0.f, ry = 0.f;
#pragma unroll 8
    for (int d = 0; d < 64; ++d) {
      rx += __shfl(qx, d) * k0s[d * 64 + lane];
      ry += __shfl(qy, d) * k1s[d * 64 + lane];
    }
    // top8 of rx and ry (value desc, tie -> lower index), lane a<8 keeps a-th
    float mvx = rx, mvy = ry;
    float keptx = 0.f, kepty = 0.f;
    int keptix = 0, keptiy = 0;
#pragma unroll
    for (int a = 0; a < 8; ++a) {
      float v = mvx; int ii = lane;
#pragma unroll
      for (int off = 32; off; off >>= 1) {
        float ov = __shfl_xor(v, off); int oi = __shfl_xor(ii, off);
        if (ov > v || (ov == v && oi < ii)) { v = ov; ii = oi; }
      }
      if (lane == a) { keptx = v; keptix = ii; }
      if (lane == ii) mvx = NEG;
      float w = mvy; int jj = lane;
#pragma unroll
      for (int off = 32; off; off >>= 1) {
        float ow = __shfl_xor(w, off); int oj = __shfl_xor(jj, off);
        if (ow > w || (ow == w && oj < jj)) { w = ow; jj = oj; }
      }
      if (lane == a) { kepty = w; keptiy = jj; }
      if (lane == jj) mvy = NEG;
    }
    // 64 pair candidates: lane = a*8+b (matches reference flatten order)
    float sa = __shfl(keptx, lane >> 3), sb = __shfl(kepty, lane & 7);
    int ia = __shfl(keptix, lane >> 3), ib = __shfl(keptiy, lane & 7);
    float mv = sa + sb;
    int pe = ia * NKEYS + ib;
    // top8 of pairs (tie -> lower flat position) + softmax
    float maxs = 0.f, denom = 0.f, kw = 0.f;
    int ke = 0;
#pragma unroll
    for (int a = 0; a < 8; ++a) {
      float v = mv; int pos = lane; int e = pe;
#pragma unroll
      for (int off = 32; off; off >>= 1) {
        float ov = __shfl_xor(v, off);
        int opos = __shfl_xor(pos, off);
        int oe = __shfl_xor(e, off);
        if (ov > v || (ov == v && opos < pos)) { v = ov; pos = opos; e = oe; }
      }
      if (a == 0) maxs = v;
      denom += __expf(v - maxs);
      if (lane == a) { kw = __expf(v - maxs); ke = e; }
      if (lane == pos) mv = NEG;
    }
    if (lane < 8) {
      topw[(size_t)n * 8 + lane] = kw / denom;
      topi[(size_t)n * 8 + lane] = ke;
    }
  }
}

// ---------------- expert branch: out[n,:] = sum_k silu(x.de_k)*w_k * ue_k ----------------
__global__ __launch_bounds__(256) void expert_kernel(const float* __restrict__ X,
                                                     const float* __restrict__ de,
                                                     const float* __restrict__ ue,
                                                     const int* __restrict__ topi,
                                                     const float* __restrict__ topw,
                                                     float* __restrict__ out) {
  const int n = blockIdx.x, t = threadIdx.x;
  __shared__ float red[4];
  __shared__ float coef_s;
  __shared__ int eidx[8];
  __shared__ float ewt[8];
  if (t < 8) {
    eidx[t] = topi[(size_t)n * 8 + t];
    ewt[t] = topw[(size_t)n * 8 + t];
  }
  const float* x = X + (size_t)n * HIDDEN + t * 8;
  float4 x0 = *(const float4*)x, x1 = *(const float4*)(x + 4);
  float a0 = 0, a1 = 0, a2 = 0, a3 = 0, a4 = 0, a5 = 0, a6 = 0, a7 = 0;
  __syncthreads();
#pragma unroll
  for (int k = 0; k < 8; ++k) {
    const float* dr = de + (size_t)eidx[k] * HIDDEN + t * 8;
    float4 d0 = *(const float4*)dr, d1 = *(const float4*)(dr + 4);
    float p = x0.x * d0.x + x0.y * d0.y + x0.z * d0.z + x0.w * d0.w +
              x1.x * d1.x + x1.y * d1.y + x1.z * d1.z + x1.w * d1.w;
#pragma unroll
    for (int off = 32; off; off >>= 1) p += __shfl_xor(p, off);
    if ((t & 63) == 0) red[t >> 6] = p;
    __syncthreads();
    if (t == 0) {
      float s = red[0] + red[1] + red[2] + red[3];
      coef_s = (s / (1.f + expf(-s))) * ewt[k];
    }
    __syncthreads();
    float c = coef_s;
    const float* ur = ue + (size_t)eidx[k] * HIDDEN + t * 8;
    float4 u0 = *(const float4*)ur, u1 = *(const float4*)(ur + 4);
    a0 += c * u0.x; a1 += c * u0.y; a2 += c * u0.z; a3 += c * u0.w;
    a4 += c * u1.x; a5 += c * u1.y; a6 += c * u1.z; a7 += c * u1.w;
  }
  float* op = out + (size_t)n * HIDDEN + t * 8;
  *(float4*)op = make_float4(a0, a1, a2, a3);
  *(float4*)(op + 4) = make_float4(a4, a5, a6, a7);
}

extern "C" void kernel_launch(void* const* d_in, const int* in_sizes, int n_in,
                              void* d_out, int out_size, void* d_ws, size_t ws_size,
                              hipStream_t stream) {
  const float* X    = (const float*)d_in[0];
  const float* Wq   = (const float*)d_in[1];
  const float* keys = (const float*)d_in[2];
  const float* de   = (const float*)d_in[3];
  const float* ue   = (const float*)d_in[4];
  const float* Wg   = (const float*)d_in[5];
  const float* Wu   = (const float*)d_in[6];
  const float* Wd   = (const float*)d_in[7];
  float* out = (float*)d_out;

  char* ws = (char*)d_ws;
  size_t o = 0;
  unsigned short* xb  = (unsigned short*)(ws + o); o += (size_t)NTOK * HIDDEN * 2;
  unsigned short* wgt = (unsigned short*)(ws + o); o += (size_t)HIDDEN * INTER * 2;
  unsigned short* wut = (unsigned short*)(ws + o); o += (size_t)HIDDEN * INTER * 2;
  unsigned short* wdt = (unsigned short*)(ws + o); o += (size_t)HIDDEN * INTER * 2;
  unsigned short* hbuf= (unsigned short*)(ws + o); o += (size_t)NTOK * INTER * 2;   // g, then h in place
  unsigned short* wqt = (unsigned short*)(ws + o); o += (size_t)RET * HIDDEN * 2;
  float* Q            = (float*)(ws + o);          o += (size_t)NTOK * RET * 4;
  int* topi           = (int*)(ws + o);            o += (size_t)NTOK * TOPK * 4;
  float* topw         = (float*)(ws + o);          o += (size_t)NTOK * TOPK * 4;

  // prep: bf16 conversions / weight transposes
  cvt_bf16<<<4096, 256, 0, stream>>>(X, xb, NTOK * HIDDEN / 4);
  transpose_cvt<<<dim3(INTER / 32, HIDDEN / 32), dim3(32, 8), 0, stream>>>(Wg, wgt, HIDDEN, INTER);
  transpose_cvt<<<dim3(INTER / 32, HIDDEN / 32), dim3(32, 8), 0, stream>>>(Wu, wut, HIDDEN, INTER);
  transpose_cvt<<<dim3(HIDDEN / 32, INTER / 32), dim3(32, 8), 0, stream>>>(Wd, wdt, INTER, HIDDEN);
  transpose_cvt<<<dim3(RET / 32, HIDDEN / 32), dim3(32, 8), 0, stream>>>(Wq, wqt, HIDDEN, RET);

  // routing branch
  gemm_bt<EPI_F32><<<dim3(1, NTOK / 128), 256, 0, stream>>>(xb, wqt, Q, nullptr,
                                                            NTOK, RET, HIDDEN);
  routing_kernel<<<256, 256, 0, stream>>>(Q, keys, topi, topw);
  expert_kernel<<<NTOK, 256, 0, stream>>>(X, de, ue, topi, topw, out);

  // dense SwiGLU MLP branch (adds onto expert states in d_out)
  gemm_bt<EPI_BF16><<<dim3(INTER / 128, NTOK / 128), 256, 0, stream>>>(
      xb, wgt, nullptr, hbuf, NTOK, INTER, HIDDEN);
  gemm_bt<EPI_SILU><<<dim3(INTER / 128, NTOK / 128), 256, 0, stream>>>(
      xb, wut, nullptr, hbuf, NTOK, INTER, HIDDEN);
  gemm_bt<EPI_ADDF32><<<dim3(HIDDEN / 128, NTOK / 128), 256, 0, stream>>>(
      hbuf, wdt, out, nullptr, NTOK, HIDDEN, INTER);
}

// Round 2
// 1735.931 us; speedup vs baseline: 1.1740x; 1.1740x over previous
//
#include <hip/hip_runtime.h>
#include <cstdint>
#include <cstddef>

#define HIDDEN 2048
#define INTER 8192
#define NTOK 8192
#define RET 128
#define NKEYS 64
#define TOPK 8

typedef __bf16 bf16_t;
typedef bf16_t bf16x8 __attribute__((ext_vector_type(8)));
typedef float floatx4 __attribute__((ext_vector_type(4)));

__device__ inline unsigned short f2bf(float f) {
  union { float f; unsigned u; } v; v.f = f;
  unsigned r = v.u + 0x7FFFu + ((v.u >> 16) & 1u);  // RNE
  return (unsigned short)(r >> 16);
}
__device__ inline float bf2f(unsigned short s) {
  union { unsigned u; float f; } v; v.u = ((unsigned)s) << 16;
  return v.f;
}

// async global->LDS, 16B per lane. lds must be the wave-uniform base; HW puts
// lane i's 16B at base + i*16.
__device__ inline void gld_lds16(unsigned short* lds, const unsigned short* g) {
  auto* l3 = reinterpret_cast<__attribute__((address_space(3))) unsigned int*>(
      reinterpret_cast<uintptr_t>(lds));
  auto* g1 = reinterpret_cast<const __attribute__((address_space(1))) unsigned int*>(
      reinterpret_cast<uintptr_t>(g));
  __builtin_amdgcn_global_load_lds(g1, l3, 16, 0, 0);
}

// ---------------- fp32 -> bf16 convert (contiguous) ----------------
__global__ __launch_bounds__(256) void cvt_bf16(const float* __restrict__ in,
                                                unsigned short* __restrict__ out,
                                                int count4) {
  for (int i = blockIdx.x * blockDim.x + threadIdx.x; i < count4;
       i += gridDim.x * blockDim.x) {
    float4 v = reinterpret_cast<const float4*>(in)[i];
    ushort4 o;
    o.x = f2bf(v.x); o.y = f2bf(v.y); o.z = f2bf(v.z); o.w = f2bf(v.w);
    reinterpret_cast<ushort4*>(out)[i] = o;
  }
}

// ---------------- fp32 [R][C] -> bf16 [C][R] transpose-convert ----------------
__global__ __launch_bounds__(256) void transpose_cvt(const float* __restrict__ in,
                                                     unsigned short* __restrict__ out,
                                                     int R, int C) {
  __shared__ float tile[32][33];
  int c0 = blockIdx.x * 32, r0 = blockIdx.y * 32;
  int tx = threadIdx.x, ty = threadIdx.y;  // block (32,8)
#pragma unroll
  for (int it = 0; it < 4; ++it)
    tile[ty + it * 8][tx] = in[(size_t)(r0 + ty + it * 8) * C + c0 + tx];
  __syncthreads();
#pragma unroll
  for (int it = 0; it < 4; ++it)
    out[(size_t)(c0 + ty + it * 8) * R + r0 + tx] = f2bf(tile[tx][ty + it * 8]);
}

// ---------------- bf16 GEMM: C[M,N] = A[M,K] * B[N,K]^T ----------------
// 128x128 tile, BK=64, 4 waves each computing 64x64 via 4x4 mfma_16x16x32_bf16.
// LDS layout XOR-swizzled: 16B chunk (row, c) of a tile lives at LDS chunk
// position row*8 + (c ^ (row&7)).  Row stride is 128B (one full bank period),
// so without the swizzle all 16 lanes of a q-group in ds_read_b128 hit the
// same 4-bank group (16-way conflict, SQ_LDS_BANK_CONFLICT=1e8 measured R0).
// With the swizzle each ds_read_b128 spreads 8 lanes per 4-bank group (floor).
enum { EPI_F32 = 0, EPI_BF16 = 1, EPI_SILU = 2, EPI_ADDF32 = 3 };

template <int MODE>
__global__ __launch_bounds__(256) void gemm_bt(const unsigned short* __restrict__ A,
                                               const unsigned short* __restrict__ B,
                                               float* __restrict__ Cf,
                                               unsigned short* __restrict__ Cb,
                                               int M, int N, int K) {
  __shared__ unsigned short As[128 * 64];
  __shared__ unsigned short Bs[128 * 64];
  const int tid = threadIdx.x;
  const int lane = tid & 63, wid = tid >> 6;
  const int wm = wid >> 1, wn = wid & 1;

  // supertile swizzle: concurrent blocks form a 16x16 region for L2/L3 reuse
  int bx = blockIdx.x, by = blockIdx.y;
  if ((gridDim.x & 15) == 0 && (gridDim.y & 15) == 0) {
    int lin = by * gridDim.x + bx;
    int stW = gridDim.x >> 4;
    int st = lin >> 8;
    int wi = lin & 255;
    bx = (st % stW) * 16 + (wi & 15);
    by = (st / stW) * 16 + (wi >> 4);
  }
  const int m0 = by * 128, n0 = bx * 128;
  const int lr = lane & 15, q = lane >> 4;
  const int swz = lr & 7;  // row&7 for all fragment rows this lane touches

  floatx4 acc[4][4];
#pragma unroll
  for (int i = 0; i < 4; ++i)
#pragma unroll
    for (int j = 0; j < 4; ++j) acc[i][j] = (floatx4){0.f, 0.f, 0.f, 0.f};

  // staging source column chunk for this lane (XOR-swizzled global gather so
  // LDS position c>>3, c&7 receives global chunk (c>>3, (c&7)^((c>>3)&7)))
  for (int k0 = 0; k0 < K; k0 += 64) {
#pragma unroll
    for (int s = 0; s < 4; ++s) {
      int c = s * 256 + wid * 64 + lane;
      int row = c >> 3, cc = (c & 7) ^ (row & 7);
      gld_lds16(&As[(s * 256 + wid * 64) * 8],
                A + (size_t)(m0 + row) * K + k0 + cc * 8);
      gld_lds16(&Bs[(s * 256 + wid * 64) * 8],
                B + (size_t)(n0 + row) * K + k0 + cc * 8);
    }
    __syncthreads();  // drains vmcnt -> LDS tiles complete
#pragma unroll
    for (int kc = 0; kc < 2; ++kc) {
      const int coff = ((kc * 4 + q) ^ swz) * 8;
      bf16x8 af[4], bfv[4];
#pragma unroll
      for (int t = 0; t < 4; ++t) {
        af[t] = *reinterpret_cast<const bf16x8*>(
            &As[(wm * 64 + t * 16 + lr) * 64 + coff]);
        bfv[t] = *reinterpret_cast<const bf16x8*>(
            &Bs[(wn * 64 + t * 16 + lr) * 64 + coff]);
      }
#pragma unroll
      for (int i = 0; i < 4; ++i)
#pragma unroll
        for (int j = 0; j < 4; ++j)
          acc[i][j] = __builtin_amdgcn_mfma_f32_16x16x32_bf16(af[i], bfv[j],
                                                              acc[i][j], 0, 0, 0);
    }
    __syncthreads();  // compute done before next-iter staging overwrites LDS
  }

  // epilogue: C/D layout col=lane&15, row=(lane>>4)*4+reg
#pragma unroll
  for (int i = 0; i < 4; ++i) {
    int rbase = m0 + wm * 64 + i * 16 + q * 4;
#pragma unroll
    for (int j = 0; j < 4; ++j) {
      int col = n0 + wn * 64 + j * 16 + lr;
#pragma unroll
      for (int r = 0; r < 4; ++r) {
        size_t idx = (size_t)(rbase + r) * N + col;
        float v = acc[i][j][r];
        if (MODE == EPI_F32) {
          Cf[idx] = v;
        } else if (MODE == EPI_BF16) {
          Cb[idx] = f2bf(v);
        } else if (MODE == EPI_SILU) {
          float g = bf2f(Cb[idx]);          // gate value written by prior GEMM
          float sg = g / (1.f + __expf(-g));
          Cb[idx] = f2bf(sg * v);           // h = silu(g) * u, in place
        } else {  // EPI_ADDF32
          Cf[idx] = v + Cf[idx];            // += expert states already in d_out
        }
      }
    }
  }
}

// ---------------- routing: per-token 2x(64x64 matvec) + top8 + pair top8 ----------------
__global__ __launch_bounds__(256) void routing_kernel(const float* __restrict__ Q,
                                                      const float* __restrict__ keys,
                                                      int* __restrict__ topi,
                                                      float* __restrict__ topw) {
  __shared__ float k0s[64 * 64];
  __shared__ float k1s[64 * 64];
  for (int i = threadIdx.x; i < 64 * 64; i += 256) {
    k0s[i] = keys[i];
    k1s[i] = keys[64 * 64 + i];
  }
  __syncthreads();
  const int lane = threadIdx.x & 63, wid = threadIdx.x >> 6;
  const int gw = blockIdx.x * 4 + wid;  // 1024 waves total
  const float NEG = -__builtin_inff();

  for (int n = gw; n < NTOK; n += 1024) {
    // bug-faithful reshape: queries[0,n,d]=Q[n/2, (n&1)*64+d]; queries[1,n,d]=Q[N/2+n/2, ...]
    int cbase = (n & 1) * 64;
    float qx = Q[(size_t)(n >> 1) * RET + cbase + lane];
    float qy = Q[(size_t)(NTOK / 2 + (n >> 1)) * RET + cbase + lane];
    float rx = 0.f, ry = 0.f;
#pragma unroll 8
    for (int d = 0; d < 64; ++d) {
      rx += __shfl(qx, d) * k0s[d * 64 + lane];
      ry += __shfl(qy, d) * k1s[d * 64 + lane];
    }
    // top8 of rx and ry (value desc, tie -> lower index), lane a<8 keeps a-th
    float mvx = rx, mvy = ry;
    float keptx = 0.f, kepty = 0.f;
    int keptix = 0, keptiy = 0;
#pragma unroll
    for (int a = 0; a < 8; ++a) {
      float v = mvx; int ii = lane;
#pragma unroll
      for (int off = 32; off; off >>= 1) {
        float ov = __shfl_xor(v, off); int oi = __shfl_xor(ii, off);
        if (ov > v || (ov == v && oi < ii)) { v = ov; ii = oi; }
      }
      if (lane == a) { keptx = v; keptix = ii; }
      if (lane == ii) mvx = NEG;
      float w = mvy; int jj = lane;
#pragma unroll
      for (int off = 32; off; off >>= 1) {
        float ow = __shfl_xor(w, off); int oj = __shfl_xor(jj, off);
        if (ow > w || (ow == w && oj < jj)) { w = ow; jj = oj; }
      }
      if (lane == a) { kepty = w; keptiy = jj; }
      if (lane == jj) mvy = NEG;
    }
    // 64 pair candidates: lane = a*8+b (matches reference flatten order)
    float sa = __shfl(keptx, lane >> 3), sb = __shfl(kepty, lane & 7);
    int ia = __shfl(keptix, lane >> 3), ib = __shfl(keptiy, lane & 7);
    float mv = sa + sb;
    int pe = ia * NKEYS + ib;
    // top8 of pairs (tie -> lower flat position) + softmax
    float maxs = 0.f, denom = 0.f, kw = 0.f;
    int ke = 0;
#pragma unroll
    for (int a = 0; a < 8; ++a) {
      float v = mv; int pos = lane; int e = pe;
#pragma unroll
      for (int off = 32; off; off >>= 1) {
        float ov = __shfl_xor(v, off);
        int opos = __shfl_xor(pos, off);
        int oe = __shfl_xor(e, off);
        if (ov > v || (ov == v && opos < pos)) { v = ov; pos = opos; e = oe; }
      }
      if (a == 0) maxs = v;
      denom += __expf(v - maxs);
      if (lane == a) { kw = __expf(v - maxs); ke = e; }
      if (lane == pos) mv = NEG;
    }
    if (lane < 8) {
      topw[(size_t)n * 8 + lane] = kw / denom;
      topi[(size_t)n * 8 + lane] = ke;
    }
  }
}

// ---------------- expert branch: out[n,:] = sum_k silu(x.de_k)*w_k * ue_k ----------------
__global__ __launch_bounds__(256) void expert_kernel(const float* __restrict__ X,
                                                     const float* __restrict__ de,
                                                     const float* __restrict__ ue,
                                                     const int* __restrict__ topi,
                                                     const float* __restrict__ topw,
                                                     float* __restrict__ out) {
  const int n = blockIdx.x, t = threadIdx.x;
  __shared__ float red[4];
  __shared__ float coef_s;
  __shared__ int eidx[8];
  __shared__ float ewt[8];
  if (t < 8) {
    eidx[t] = topi[(size_t)n * 8 + t];
    ewt[t] = topw[(size_t)n * 8 + t];
  }
  const float* x = X + (size_t)n * HIDDEN + t * 8;
  float4 x0 = *(const float4*)x, x1 = *(const float4*)(x + 4);
  float a0 = 0, a1 = 0, a2 = 0, a3 = 0, a4 = 0, a5 = 0, a6 = 0, a7 = 0;
  __syncthreads();
#pragma unroll
  for (int k = 0; k < 8; ++k) {
    const float* dr = de + (size_t)eidx[k] * HIDDEN + t * 8;
    float4 d0 = *(const float4*)dr, d1 = *(const float4*)(dr + 4);
    float p = x0.x * d0.x + x0.y * d0.y + x0.z * d0.z + x0.w * d0.w +
              x1.x * d1.x + x1.y * d1.y + x1.z * d1.z + x1.w * d1.w;
#pragma unroll
    for (int off = 32; off; off >>= 1) p += __shfl_xor(p, off);
    if ((t & 63) == 0) red[t >> 6] = p;
    __syncthreads();
    if (t == 0) {
      float s = red[0] + red[1] + red[2] + red[3];
      coef_s = (s / (1.f + expf(-s))) * ewt[k];
    }
    __syncthreads();
    float c = coef_s;
    const float* ur = ue + (size_t)eidx[k] * HIDDEN + t * 8;
    float4 u0 = *(const float4*)ur, u1 = *(const float4*)(ur + 4);
    a0 += c * u0.x; a1 += c * u0.y; a2 += c * u0.z; a3 += c * u0.w;
    a4 += c * u1.x; a5 += c * u1.y; a6 += c * u1.z; a7 += c * u1.w;
  }
  float* op = out + (size_t)n * HIDDEN + t * 8;
  *(float4*)op = make_float4(a0, a1, a2, a3);
  *(float4*)(op + 4) = make_float4(a4, a5, a6, a7);
}

extern "C" void kernel_launch(void* const* d_in, const int* in_sizes, int n_in,
                              void* d_out, int out_size, void* d_ws, size_t ws_size,
                              hipStream_t stream) {
  const float* X    = (const float*)d_in[0];
  const float* Wq   = (const float*)d_in[1];
  const float* keys = (const float*)d_in[2];
  const float* de   = (const float*)d_in[3];
  const float* ue   = (const float*)d_in[4];
  const float* Wg   = (const float*)d_in[5];
  const float* Wu   = (const float*)d_in[6];
  const float* Wd   = (const float*)d_in[7];
  float* out = (float*)d_out;

  char* ws = (char*)d_ws;
  size_t o = 0;
  unsigned short* xb  = (unsigned short*)(ws + o); o += (size_t)NTOK * HIDDEN * 2;
  unsigned short* wgt = (unsigned short*)(ws + o); o += (size_t)HIDDEN * INTER * 2;
  unsigned short* wut = (unsigned short*)(ws + o); o += (size_t)HIDDEN * INTER * 2;
  unsigned short* wdt = (unsigned short*)(ws + o); o += (size_t)HIDDEN * INTER * 2;
  unsigned short* hbuf= (unsigned short*)(ws + o); o += (size_t)NTOK * INTER * 2;   // g, then h in place
  unsigned short* wqt = (unsigned short*)(ws + o); o += (size_t)RET * HIDDEN * 2;
  float* Q            = (float*)(ws + o);          o += (size_t)NTOK * RET * 4;
  int* topi           = (int*)(ws + o);            o += (size_t)NTOK * TOPK * 4;
  float* topw         = (float*)(ws + o);          o += (size_t)NTOK * TOPK * 4;

  // prep: bf16 conversions / weight transposes
  cvt_bf16<<<4096, 256, 0, stream>>>(X, xb, NTOK * HIDDEN / 4);
  transpose_cvt<<<dim3(INTER / 32, HIDDEN / 32), dim3(32, 8), 0, stream>>>(Wg, wgt, HIDDEN, INTER);
  transpose_cvt<<<dim3(INTER / 32, HIDDEN / 32), dim3(32, 8), 0, stream>>>(Wu, wut, HIDDEN, INTER);
  transpose_cvt<<<dim3(HIDDEN / 32, INTER / 32), dim3(32, 8), 0, stream>>>(Wd, wdt, INTER, HIDDEN);
  transpose_cvt<<<dim3(RET / 32, HIDDEN / 32), dim3(32, 8), 0, stream>>>(Wq, wqt, HIDDEN, RET);

  // routing branch
  gemm_bt<EPI_F32><<<dim3(1, NTOK / 128), 256, 0, stream>>>(xb, wqt, Q, nullptr,
                                                            NTOK, RET, HIDDEN);
  routing_kernel<<<256, 256, 0, stream>>>(Q, keys, topi, topw);
  expert_kernel<<<NTOK, 256, 0, stream>>>(X, de, ue, topi, topw, out);

  // dense SwiGLU MLP branch (adds onto expert states in d_out)
  gemm_bt<EPI_BF16><<<dim3(INTER / 128, NTOK / 128), 256, 0, stream>>>(
      xb, wgt, nullptr, hbuf, NTOK, INTER, HIDDEN);
  gemm_bt<EPI_SILU><<<dim3(INTER / 128, NTOK / 128), 256, 0, stream>>>(
      xb, wut, nullptr, hbuf, NTOK, INTER, HIDDEN);
  gemm_bt<EPI_ADDF32><<<dim3(HIDDEN / 128, NTOK / 128), 256, 0, stream>>>(
      hbuf, wdt, out, nullptr, NTOK, HIDDEN, INTER);
}

// Round 3
// 1559.671 us; speedup vs baseline: 1.3067x; 1.1130x over previous
//
#include <hip/hip_runtime.h>
#include <cstdint>
#include <cstddef>

#define HIDDEN 2048
#define INTER 8192
#define NTOK 8192
#define RET 128
#define NKEYS 64
#define TOPK 8

typedef __bf16 bf16_t;
typedef bf16_t bf16x8 __attribute__((ext_vector_type(8)));
typedef float floatx4 __attribute__((ext_vector_type(4)));

__device__ inline unsigned short f2bf(float f) {
  union { float f; unsigned u; } v; v.f = f;
  unsigned r = v.u + 0x7FFFu + ((v.u >> 16) & 1u);  // RNE
  return (unsigned short)(r >> 16);
}
__device__ inline float bf2f(unsigned short s) {
  union { unsigned u; float f; } v; v.u = ((unsigned)s) << 16;
  return v.f;
}

// async global->LDS, 16B per lane. lds must be the wave-uniform base; HW puts
// lane i's 16B at base + i*16.
__device__ inline void gld_lds16(unsigned short* lds, const unsigned short* g) {
  auto* l3 = reinterpret_cast<__attribute__((address_space(3))) unsigned int*>(
      reinterpret_cast<uintptr_t>(lds));
  auto* g1 = reinterpret_cast<const __attribute__((address_space(1))) unsigned int*>(
      reinterpret_cast<uintptr_t>(g));
  __builtin_amdgcn_global_load_lds(g1, l3, 16, 0, 0);
}

// XCD-aware block remap. Dispatch round-robins linear block id across the 8
// XCDs (lin%8). Give XCD k a contiguous column band of width gx/8 traversed
// serpentine, so its concurrent ~64 blocks keep the band's B-slabs resident
// in its private 4MiB L2 while A-slabs march through L3 once device-wide.
// (R1's 16x16 supertile ignored the %8 scatter: FETCH 360->660MB. Reverted.)
__device__ inline void xcd_map(int gx, int gy, int& bx, int& by) {
  if ((gx & 7) != 0) return;
  int lin = by * gx + bx;
  int W = gx >> 3;
  int xcd = lin & 7;
  int j = lin >> 3;
  int r = j / W, c = j % W;
  if (r & 1) c = W - 1 - c;  // serpentine for adjacency at band turns
  bx = xcd * W + c;
  by = r;
}

// ---------------- fp32 -> bf16 convert (contiguous) ----------------
__global__ __launch_bounds__(256) void cvt_bf16(const float* __restrict__ in,
                                                unsigned short* __restrict__ out,
                                                int count4) {
  for (int i = blockIdx.x * blockDim.x + threadIdx.x; i < count4;
       i += gridDim.x * blockDim.x) {
    float4 v = reinterpret_cast<const float4*>(in)[i];
    ushort4 o;
    o.x = f2bf(v.x); o.y = f2bf(v.y); o.z = f2bf(v.z); o.w = f2bf(v.w);
    reinterpret_cast<ushort4*>(out)[i] = o;
  }
}

// ---------------- fp32 [R][C] -> bf16 [C][R] transpose-convert ----------------
__global__ __launch_bounds__(256) void transpose_cvt(const float* __restrict__ in,
                                                     unsigned short* __restrict__ out,
                                                     int R, int C) {
  __shared__ float tile[32][33];
  int c0 = blockIdx.x * 32, r0 = blockIdx.y * 32;
  int tx = threadIdx.x, ty = threadIdx.y;  // block (32,8)
#pragma unroll
  for (int it = 0; it < 4; ++it)
    tile[ty + it * 8][tx] = in[(size_t)(r0 + ty + it * 8) * C + c0 + tx];
  __syncthreads();
#pragma unroll
  for (int it = 0; it < 4; ++it)
    out[(size_t)(c0 + ty + it * 8) * R + r0 + tx] = f2bf(tile[tx][ty + it * 8]);
}

// ---------------- bf16 GEMM: C[M,N] = A[M,K] * B[N,K]^T ----------------
// 128x128 tile, BK=64, 4 waves each computing 64x64 via 4x4 mfma_16x16x32_bf16.
// LDS XOR-swizzle: chunk (row,c) stored at position c^(row&7) within the row.
// Row stride is 128B = one bank period; without the swizzle all 16 lanes of a
// q-group hit one 4-bank group (R0: SQ_LDS_BANK_CONFLICT=1e8; R1 w/ swizzle: 0).
enum { EPI_F32 = 0, EPI_ADDF32 = 3 };

template <int MODE>
__global__ __launch_bounds__(256) void gemm_bt(const unsigned short* __restrict__ A,
                                               const unsigned short* __restrict__ B,
                                               float* __restrict__ Cf,
                                               int M, int N, int K) {
  __shared__ unsigned short As[128 * 64];
  __shared__ unsigned short Bs[128 * 64];
  const int tid = threadIdx.x;
  const int lane = tid & 63, wid = tid >> 6;
  const int wm = wid >> 1, wn = wid & 1;
  int bx = blockIdx.x, by = blockIdx.y;
  xcd_map(gridDim.x, gridDim.y, bx, by);
  const int m0 = by * 128, n0 = bx * 128;
  const int lr = lane & 15, q = lane >> 4;
  const int swz = lr & 7;

  floatx4 acc[4][4];
#pragma unroll
  for (int i = 0; i < 4; ++i)
#pragma unroll
    for (int j = 0; j < 4; ++j) acc[i][j] = (floatx4){0.f, 0.f, 0.f, 0.f};

  for (int k0 = 0; k0 < K; k0 += 64) {
#pragma unroll
    for (int s = 0; s < 4; ++s) {
      int c = s * 256 + wid * 64 + lane;
      int row = c >> 3, cc = (c & 7) ^ (row & 7);
      gld_lds16(&As[(s * 256 + wid * 64) * 8],
                A + (size_t)(m0 + row) * K + k0 + cc * 8);
      gld_lds16(&Bs[(s * 256 + wid * 64) * 8],
                B + (size_t)(n0 + row) * K + k0 + cc * 8);
    }
    __syncthreads();
#pragma unroll
    for (int kc = 0; kc < 2; ++kc) {
      const int coff = ((kc * 4 + q) ^ swz) * 8;
      bf16x8 af[4], bfv[4];
#pragma unroll
      for (int t = 0; t < 4; ++t) {
        af[t] = *reinterpret_cast<const bf16x8*>(
            &As[(wm * 64 + t * 16 + lr) * 64 + coff]);
        bfv[t] = *reinterpret_cast<const bf16x8*>(
            &Bs[(wn * 64 + t * 16 + lr) * 64 + coff]);
      }
#pragma unroll
      for (int i = 0; i < 4; ++i)
#pragma unroll
        for (int j = 0; j < 4; ++j)
          acc[i][j] = __builtin_amdgcn_mfma_f32_16x16x32_bf16(af[i], bfv[j],
                                                              acc[i][j], 0, 0, 0);
    }
    __syncthreads();
  }

  // epilogue: C/D layout col=lane&15, row=(lane>>4)*4+reg
#pragma unroll
  for (int i = 0; i < 4; ++i) {
    int rbase = m0 + wm * 64 + i * 16 + q * 4;
#pragma unroll
    for (int j = 0; j < 4; ++j) {
      int col = n0 + wn * 64 + j * 16 + lr;
#pragma unroll
      for (int r = 0; r < 4; ++r) {
        size_t idx = (size_t)(rbase + r) * N + col;
        float v = acc[i][j][r];
        if (MODE == EPI_F32) Cf[idx] = v;
        else Cf[idx] = v + Cf[idx];  // += expert states already in d_out
      }
    }
  }
}

// ---------------- fused gate+up GEMM: H = silu(A*Bg^T) .* (A*Bu^T), bf16 out --
// Stages A once for both B operands: kills one full pass over A plus the
// 134MB g-write + 134MB g-read of the two-dispatch version.
__global__ __launch_bounds__(256, 2) void gemm_gateup(
    const unsigned short* __restrict__ A, const unsigned short* __restrict__ Bg,
    const unsigned short* __restrict__ Bu, unsigned short* __restrict__ H,
    int M, int N, int K) {
  __shared__ unsigned short As[128 * 64];
  __shared__ unsigned short Bgs[128 * 64];
  __shared__ unsigned short Bus[128 * 64];
  const int tid = threadIdx.x;
  const int lane = tid & 63, wid = tid >> 6;
  const int wm = wid >> 1, wn = wid & 1;
  int bx = blockIdx.x, by = blockIdx.y;
  xcd_map(gridDim.x, gridDim.y, bx, by);
  const int m0 = by * 128, n0 = bx * 128;
  const int lr = lane & 15, q = lane >> 4;
  const int swz = lr & 7;

  floatx4 accg[4][4], accu[4][4];
#pragma unroll
  for (int i = 0; i < 4; ++i)
#pragma unroll
    for (int j = 0; j < 4; ++j) {
      accg[i][j] = (floatx4){0.f, 0.f, 0.f, 0.f};
      accu[i][j] = (floatx4){0.f, 0.f, 0.f, 0.f};
    }

  for (int k0 = 0; k0 < K; k0 += 64) {
#pragma unroll
    for (int s = 0; s < 4; ++s) {
      int c = s * 256 + wid * 64 + lane;
      int row = c >> 3, cc = (c & 7) ^ (row & 7);
      size_t arow = (size_t)(m0 + row) * K + k0 + cc * 8;
      size_t brow = (size_t)(n0 + row) * K + k0 + cc * 8;
      gld_lds16(&As[(s * 256 + wid * 64) * 8], A + arow);
      gld_lds16(&Bgs[(s * 256 + wid * 64) * 8], Bg + brow);
      gld_lds16(&Bus[(s * 256 + wid * 64) * 8], Bu + brow);
    }
    __syncthreads();
#pragma unroll
    for (int kc = 0; kc < 2; ++kc) {
      const int coff = ((kc * 4 + q) ^ swz) * 8;
      bf16x8 af[4], bgf[4], buf[4];
#pragma unroll
      for (int t = 0; t < 4; ++t) {
        af[t] = *reinterpret_cast<const bf16x8*>(
            &As[(wm * 64 + t * 16 + lr) * 64 + coff]);
        bgf[t] = *reinterpret_cast<const bf16x8*>(
            &Bgs[(wn * 64 + t * 16 + lr) * 64 + coff]);
        buf[t] = *reinterpret_cast<const bf16x8*>(
            &Bus[(wn * 64 + t * 16 + lr) * 64 + coff]);
      }
#pragma unroll
      for (int i = 0; i < 4; ++i)
#pragma unroll
        for (int j = 0; j < 4; ++j) {
          accg[i][j] = __builtin_amdgcn_mfma_f32_16x16x32_bf16(af[i], bgf[j],
                                                               accg[i][j], 0, 0, 0);
          accu[i][j] = __builtin_amdgcn_mfma_f32_16x16x32_bf16(af[i], buf[j],
                                                               accu[i][j], 0, 0, 0);
        }
    }
    __syncthreads();
  }

#pragma unroll
  for (int i = 0; i < 4; ++i) {
    int rbase = m0 + wm * 64 + i * 16 + q * 4;
#pragma unroll
    for (int j = 0; j < 4; ++j) {
      int col = n0 + wn * 64 + j * 16 + lr;
#pragma unroll
      for (int r = 0; r < 4; ++r) {
        float g = accg[i][j][r];
        float h = (g / (1.f + __expf(-g))) * accu[i][j][r];
        H[(size_t)(rbase + r) * N + col] = f2bf(h);
      }
    }
  }
}

// ---------------- routing: per-token 2x(64x64 matvec) + top8 + pair top8 ----------------
__global__ __launch_bounds__(256) void routing_kernel(const float* __restrict__ Q,
                                                      const float* __restrict__ keys,
                                                      int* __restrict__ topi,
                                                      float* __restrict__ topw) {
  __shared__ float k0s[64 * 64];
  __shared__ float k1s[64 * 64];
  for (int i = threadIdx.x; i < 64 * 64; i += 256) {
    k0s[i] = keys[i];
    k1s[i] = keys[64 * 64 + i];
  }
  __syncthreads();
  const int lane = threadIdx.x & 63, wid = threadIdx.x >> 6;
  const int gw = blockIdx.x * 4 + wid;  // 1024 waves total
  const float NEG = -__builtin_inff();

  for (int n = gw; n < NTOK; n += 1024) {
    // bug-faithful reshape: queries[0,n,d]=Q[n/2, (n&1)*64+d]; queries[1,n,d]=Q[N/2+n/2, ...]
    int cbase = (n & 1) * 64;
    float qx = Q[(size_t)(n >> 1) * RET + cbase + lane];
    float qy = Q[(size_t)(NTOK / 2 + (n >> 1)) * RET + cbase + lane];
    float rx = 0.f, ry = 0.f;
#pragma unroll 8
    for (int d = 0; d < 64; ++d) {
      rx += __shfl(qx, d) * k0s[d * 64 + lane];
      ry += __shfl(qy, d) * k1s[d * 64 + lane];
    }
    float mvx = rx, mvy = ry;
    float keptx = 0.f, kepty = 0.f;
    int keptix = 0, keptiy = 0;
#pragma unroll
    for (int a = 0; a < 8; ++a) {
      float v = mvx; int ii = lane;
#pragma unroll
      for (int off = 32; off; off >>= 1) {
        float ov = __shfl_xor(v, off); int oi = __shfl_xor(ii, off);
        if (ov > v || (ov == v && oi < ii)) { v = ov; ii = oi; }
      }
      if (lane == a) { keptx = v; keptix = ii; }
      if (lane == ii) mvx = NEG;
      float w = mvy; int jj = lane;
#pragma unroll
      for (int off = 32; off; off >>= 1) {
        float ow = __shfl_xor(w, off); int oj = __shfl_xor(jj, off);
        if (ow > w || (ow == w && oj < jj)) { w = ow; jj = oj; }
      }
      if (lane == a) { kepty = w; keptiy = jj; }
      if (lane == jj) mvy = NEG;
    }
    float sa = __shfl(keptx, lane >> 3), sb = __shfl(kepty, lane & 7);
    int ia = __shfl(keptix, lane >> 3), ib = __shfl(keptiy, lane & 7);
    float mv = sa + sb;
    int pe = ia * NKEYS + ib;
    float maxs = 0.f, denom = 0.f, kw = 0.f;
    int ke = 0;
#pragma unroll
    for (int a = 0; a < 8; ++a) {
      float v = mv; int pos = lane; int e = pe;
#pragma unroll
      for (int off = 32; off; off >>= 1) {
        float ov = __shfl_xor(v, off);
        int opos = __shfl_xor(pos, off);
        int oe = __shfl_xor(e, off);
        if (ov > v || (ov == v && opos < pos)) { v = ov; pos = opos; e = oe; }
      }
      if (a == 0) maxs = v;
      denom += __expf(v - maxs);
      if (lane == a) { kw = __expf(v - maxs); ke = e; }
      if (lane == pos) mv = NEG;
    }
    if (lane < 8) {
      topw[(size_t)n * 8 + lane] = kw / denom;
      topi[(size_t)n * 8 + lane] = ke;
    }
  }
}

// ---------------- expert branch: out[n,:] = sum_k silu(x.de_k)*w_k * ue_k ----------------
__global__ __launch_bounds__(256) void expert_kernel(const float* __restrict__ X,
                                                     const float* __restrict__ de,
                                                     const float* __restrict__ ue,
                                                     const int* __restrict__ topi,
                                                     const float* __restrict__ topw,
                                                     float* __restrict__ out) {
  const int n = blockIdx.x, t = threadIdx.x;
  __shared__ float red[4];
  __shared__ float coef_s;
  __shared__ int eidx[8];
  __shared__ float ewt[8];
  if (t < 8) {
    eidx[t] = topi[(size_t)n * 8 + t];
    ewt[t] = topw[(size_t)n * 8 + t];
  }
  const float* x = X + (size_t)n * HIDDEN + t * 8;
  float4 x0 = *(const float4*)x, x1 = *(const float4*)(x + 4);
  float a0 = 0, a1 = 0, a2 = 0, a3 = 0, a4 = 0, a5 = 0, a6 = 0, a7 = 0;
  __syncthreads();
#pragma unroll
  for (int k = 0; k < 8; ++k) {
    const float* dr = de + (size_t)eidx[k] * HIDDEN + t * 8;
    float4 d0 = *(const float4*)dr, d1 = *(const float4*)(dr + 4);
    float p = x0.x * d0.x + x0.y * d0.y + x0.z * d0.z + x0.w * d0.w +
              x1.x * d1.x + x1.y * d1.y + x1.z * d1.z + x1.w * d1.w;
#pragma unroll
    for (int off = 32; off; off >>= 1) p += __shfl_xor(p, off);
    if ((t & 63) == 0) red[t >> 6] = p;
    __syncthreads();
    if (t == 0) {
      float s = red[0] + red[1] + red[2] + red[3];
      coef_s = (s / (1.f + expf(-s))) * ewt[k];
    }
    __syncthreads();
    float c = coef_s;
    const float* ur = ue + (size_t)eidx[k] * HIDDEN + t * 8;
    float4 u0 = *(const float4*)ur, u1 = *(const float4*)(ur + 4);
    a0 += c * u0.x; a1 += c * u0.y; a2 += c * u0.z; a3 += c * u0.w;
    a4 += c * u1.x; a5 += c * u1.y; a6 += c * u1.z; a7 += c * u1.w;
  }
  float* op = out + (size_t)n * HIDDEN + t * 8;
  *(float4*)op = make_float4(a0, a1, a2, a3);
  *(float4*)(op + 4) = make_float4(a4, a5, a6, a7);
}

extern "C" void kernel_launch(void* const* d_in, const int* in_sizes, int n_in,
                              void* d_out, int out_size, void* d_ws, size_t ws_size,
                              hipStream_t stream) {
  const float* X    = (const float*)d_in[0];
  const float* Wq   = (const float*)d_in[1];
  const float* keys = (const float*)d_in[2];
  const float* de   = (const float*)d_in[3];
  const float* ue   = (const float*)d_in[4];
  const float* Wg   = (const float*)d_in[5];
  const float* Wu   = (const float*)d_in[6];
  const float* Wd   = (const float*)d_in[7];
  float* out = (float*)d_out;

  char* ws = (char*)d_ws;
  size_t o = 0;
  unsigned short* xb  = (unsigned short*)(ws + o); o += (size_t)NTOK * HIDDEN * 2;
  unsigned short* wgt = (unsigned short*)(ws + o); o += (size_t)HIDDEN * INTER * 2;
  unsigned short* wut = (unsigned short*)(ws + o); o += (size_t)HIDDEN * INTER * 2;
  unsigned short* wdt = (unsigned short*)(ws + o); o += (size_t)HIDDEN * INTER * 2;
  unsigned short* hbuf= (unsigned short*)(ws + o); o += (size_t)NTOK * INTER * 2;
  unsigned short* wqt = (unsigned short*)(ws + o); o += (size_t)RET * HIDDEN * 2;
  float* Q            = (float*)(ws + o);          o += (size_t)NTOK * RET * 4;
  int* topi           = (int*)(ws + o);            o += (size_t)NTOK * TOPK * 4;
  float* topw         = (float*)(ws + o);          o += (size_t)NTOK * TOPK * 4;

  // prep: bf16 conversions / weight transposes
  cvt_bf16<<<4096, 256, 0, stream>>>(X, xb, NTOK * HIDDEN / 4);
  transpose_cvt<<<dim3(INTER / 32, HIDDEN / 32), dim3(32, 8), 0, stream>>>(Wg, wgt, HIDDEN, INTER);
  transpose_cvt<<<dim3(INTER / 32, HIDDEN / 32), dim3(32, 8), 0, stream>>>(Wu, wut, HIDDEN, INTER);
  transpose_cvt<<<dim3(HIDDEN / 32, INTER / 32), dim3(32, 8), 0, stream>>>(Wd, wdt, INTER, HIDDEN);
  transpose_cvt<<<dim3(RET / 32, HIDDEN / 32), dim3(32, 8), 0, stream>>>(Wq, wqt, HIDDEN, RET);

  // routing branch
  gemm_bt<EPI_F32><<<dim3(1, NTOK / 128), 256, 0, stream>>>(xb, wqt, Q,
                                                            NTOK, RET, HIDDEN);
  routing_kernel<<<256, 256, 0, stream>>>(Q, keys, topi, topw);
  expert_kernel<<<NTOK, 256, 0, stream>>>(X, de, ue, topi, topw, out);

  // dense SwiGLU MLP branch
  gemm_gateup<<<dim3(INTER / 128, NTOK / 128), 256, 0, stream>>>(
      xb, wgt, wut, hbuf, NTOK, INTER, HIDDEN);
  gemm_bt<EPI_ADDF32><<<dim3(HIDDEN / 128, NTOK / 128), 256, 0, stream>>>(
      hbuf, wdt, out, NTOK, HIDDEN, INTER);
}